// Round 10
// baseline (362.375 us; speedup 1.0000x reference)
//
#include <hip/hip_runtime.h>
#include <hip/hip_bf16.h>

// Problem constants
constexpr int S      = 4096;
constexpr int DMODEL = 1024;
constexpr int H      = 16;
constexpr int DK     = 64;

typedef __attribute__((ext_vector_type(8))) short          short8;
typedef __attribute__((ext_vector_type(4))) short          short4v;
typedef __attribute__((ext_vector_type(4))) float          float4v;
typedef __attribute__((ext_vector_type(4))) unsigned short ushort4v;
typedef __attribute__((ext_vector_type(8))) unsigned short ushort8;

// RNE float -> bf16 (bit pattern), and back
__device__ __forceinline__ unsigned short f2bf(float x) {
    unsigned u = __builtin_bit_cast(unsigned, x);
    u += 0x7FFFu + ((u >> 16) & 1u);
    return (unsigned short)(u >> 16);
}
__device__ __forceinline__ float bf2f(unsigned short h) {
    unsigned u = ((unsigned)h) << 16;
    return __builtin_bit_cast(float, u);
}
__device__ __forceinline__ float fexp2(float x) { return __builtin_amdgcn_exp2f(x); }

// async global->LDS DMA, 16B per lane; lds dest = wave-uniform base + lane*16
__device__ __forceinline__ void gl_lds16(const unsigned short* g, unsigned short* l) {
    __builtin_amdgcn_global_load_lds(
        (const __attribute__((address_space(1))) unsigned int*)g,
        (__attribute__((address_space(3))) unsigned int*)l, 16, 0, 0);
}

// ---------------------------------------------------------------------------
// Prep 1: elementwise split of X inputs (round-3 exact).
// ---------------------------------------------------------------------------
__global__ __launch_bounds__(256) void split_inputs(const float* __restrict__ Q,
                                                    const float* __restrict__ K,
                                                    const float* __restrict__ V,
                                                    unsigned short* __restrict__ QH,
                                                    unsigned short* __restrict__ QL,
                                                    unsigned short* __restrict__ KH,
                                                    unsigned short* __restrict__ KL,
                                                    unsigned short* __restrict__ Vb)
{
    const int z = blockIdx.z;
    const size_t base = ((size_t)blockIdx.x * 256 + threadIdx.x) * 8;
    const float* src = (z == 0) ? Q : (z == 1) ? K : V;
    const float4 a = *(const float4*)(src + base);
    const float4 b = *(const float4*)(src + base + 4);
    const float xs[8] = {a.x, a.y, a.z, a.w, b.x, b.y, b.z, b.w};
    ushort8 hv, lv;
#pragma unroll
    for (int j = 0; j < 8; ++j) {
        const unsigned short h = f2bf(xs[j]);
        hv[j] = h;
        lv[j] = f2bf(xs[j] - bf2f(h));
    }
    if (z == 0)      { *(ushort8*)(QH + base) = hv; *(ushort8*)(QL + base) = lv; }
    else if (z == 1) { *(ushort8*)(KH + base) = hv; *(ushort8*)(KL + base) = lv; }
    else             { *(ushort8*)(Vb + base) = hv; }
}

// ---------------------------------------------------------------------------
// Elementwise split of fp32 Kc -> bf16 hi/lo (round-5 validated).
// ---------------------------------------------------------------------------
__global__ __launch_bounds__(256) void conv_k(const float* __restrict__ Kc,
                                              unsigned short* __restrict__ KH,
                                              unsigned short* __restrict__ KL)
{
    const size_t base = ((size_t)blockIdx.x * 256 + threadIdx.x) * 8;
    const float4 a = *(const float4*)(Kc + base);
    const float4 b = *(const float4*)(Kc + base + 4);
    const float xs[8] = {a.x, a.y, a.z, a.w, b.x, b.y, b.z, b.w};
    ushort8 hv, lv;
#pragma unroll
    for (int j = 0; j < 8; ++j) {
        const unsigned short h = f2bf(xs[j]);
        hv[j] = h;
        lv[j] = f2bf(xs[j] - bf2f(h));
    }
    *(ushort8*)(KH + base) = hv;
    *(ushort8*)(KL + base) = lv;
}

// ---------------------------------------------------------------------------
// Transpose fp32 Vc [s][1024] -> bf16 Vt [n][4096] (round-7 validated).
// ---------------------------------------------------------------------------
__global__ __launch_bounds__(256) void transpose_v(const float* __restrict__ Vc,
                                                   unsigned short* __restrict__ Vt)
{
    __shared__ unsigned short Ts[64][68];
    const int t  = threadIdx.x;
    const int s0 = blockIdx.x * 64;
    const int n0 = blockIdx.y * 64;
#pragma unroll
    for (int i = 0; i < 4; ++i) {
        const int row = (t >> 4) + i * 16;     // s index
        const int col = (t & 15) * 4;          // n index
        const float4 v = *(const float4*)&Vc[(size_t)(s0 + row) * 1024 + n0 + col];
        Ts[row][col + 0] = f2bf(v.x); Ts[row][col + 1] = f2bf(v.y);
        Ts[row][col + 2] = f2bf(v.z); Ts[row][col + 3] = f2bf(v.w);
    }
    __syncthreads();
#pragma unroll
    for (int i = 0; i < 4; ++i) {
        const int n  = (t >> 4) + i * 16;      // out row (n)
        const int sb = (t & 15) * 4;           // out col (s)
        ushort4v v;
#pragma unroll
        for (int j = 0; j < 4; ++j) v[j] = Ts[sb + j][n];
        *(ushort4v*)&Vt[(size_t)(n0 + n) * 4096 + s0 + sb] = v;
    }
}

// ---------------------------------------------------------------------------
// Prep 2: all four weight transposes fused into one launch.
// blockIdx.z: z>>4 selects matrix (0=WQ,1=WK,2=WV,3=WO), z&15 = slab.
// Body identical to round-3-validated transpose_w.
// ---------------------------------------------------------------------------
__global__ __launch_bounds__(256) void transpose_w_all(
    const float* __restrict__ WQ, const float* __restrict__ WK,
    const float* __restrict__ WV, const float* __restrict__ WO,
    unsigned short* __restrict__ WqtH, unsigned short* __restrict__ WqtL,
    unsigned short* __restrict__ WktH, unsigned short* __restrict__ WktL,
    unsigned short* __restrict__ Wvt,  unsigned short* __restrict__ WOt)
{
    __shared__ float Ts[64][65];
    const int t     = threadIdx.x;
    const int which = blockIdx.z >> 4;
    const int z     = blockIdx.z & 15;
    const int r0    = blockIdx.x * 64;

    const float* in;
    unsigned short *oh, *ol;
    int z_mult, rstride;
    if (which == 0)      { in = WQ; oh = WqtH; ol = WqtL; z_mult = 65536; rstride = 64; }
    else if (which == 1) { in = WK; oh = WktH; ol = WktL; z_mult = 65536; rstride = 64; }
    else if (which == 2) { in = WV; oh = Wvt;  ol = nullptr; z_mult = 65536; rstride = 64; }
    else                 { in = WO; oh = WOt;  ol = nullptr; z_mult = 64;    rstride = 1024; }

    const float* src = in + (size_t)z * z_mult;
#pragma unroll
    for (int i = 0; i < 4; ++i) {
        const int row = (t >> 4) + i * 16;
        const int col = (t & 15) * 4;
        const float4 v = *(const float4*)&src[(size_t)(r0 + row) * rstride + col];
        Ts[row][col + 0] = v.x; Ts[row][col + 1] = v.y;
        Ts[row][col + 2] = v.z; Ts[row][col + 3] = v.w;
    }
    __syncthreads();
#pragma unroll
    for (int i = 0; i < 4; ++i) {
        const int c  = (t >> 4) + i * 16;
        const int rb = (t & 15) * 4;
        ushort4v hv, lv;
#pragma unroll
        for (int j = 0; j < 4; ++j) {
            const float x = Ts[rb + j][c];
            const unsigned short h = f2bf(x);
            hv[j] = h;
            lv[j] = f2bf(x - bf2f(h));
        }
        const size_t o = (size_t)(z * 64 + c) * 1024 + r0 + rb;
        *(ushort4v*)&oh[o] = hv;
        if (ol) *(ushort4v*)&ol[o] = lv;
    }
}

// ---------------------------------------------------------------------------
// bf16 MFMA GEMM core (round-8: global_load_lds width=16 staging).
// ---------------------------------------------------------------------------
template <bool SPLIT>
__device__ __forceinline__ void gemm_core(unsigned short* __restrict__ sm,
                                          const unsigned short* __restrict__ Ah,
                                          const unsigned short* __restrict__ Al,
                                          const unsigned short* __restrict__ Bh,
                                          const unsigned short* __restrict__ Bl,
                                          float* __restrict__ C,
                                          int m0, int n0)
{
    unsigned short* AsH = sm;            // [128][32]
    unsigned short* BsH = sm + 4096;
    unsigned short* AsL = sm + 8192;     // SPLIT only
    unsigned short* BsL = sm + 12288;

    const int t    = threadIdx.x;
    const int wave = t >> 6;
    const int lane = t & 63;
    const int quad = lane >> 4;
    const int l15  = lane & 15;
    const int wm   = (wave & 1) * 64;
    const int wn   = (wave >> 1) * 64;

    float4v acc[4][4];
#pragma unroll
    for (int mi = 0; mi < 4; ++mi)
#pragma unroll
        for (int ni = 0; ni < 4; ++ni)
#pragma unroll
            for (int r = 0; r < 4; ++r) acc[mi][ni][r] = 0.f;

    for (int k0 = 0; k0 < 1024; k0 += 32) {
        __syncthreads();   // prior iteration's LDS reads complete
#pragma unroll
        for (int i = 0; i < 2; ++i) {
            const int c   = t + 256 * i;
            const int row = c >> 2;
            const int kc  = (c & 3) * 8;
            const int lb  = (i * 256 + wave * 64) * 8;   // wave-uniform base (shorts)
            gl_lds16(&Ah[(size_t)(m0 + row) * 1024 + k0 + kc], AsH + lb);
            gl_lds16(&Bh[(size_t)(n0 + row) * 1024 + k0 + kc], BsH + lb);
            if (SPLIT) {
                gl_lds16(&Al[(size_t)(m0 + row) * 1024 + k0 + kc], AsL + lb);
                gl_lds16(&Bl[(size_t)(n0 + row) * 1024 + k0 + kc], BsL + lb);
            }
        }
        __syncthreads();   // vmcnt drained before barrier -> data visible

        short8 afh[4], bfh[4], afl[4], bfl[4];
#pragma unroll
        for (int mi = 0; mi < 4; ++mi)
            afh[mi] = *(const short8*)&AsH[(wm + mi * 16 + l15) * 32 + quad * 8];
#pragma unroll
        for (int ni = 0; ni < 4; ++ni)
            bfh[ni] = *(const short8*)&BsH[(wn + ni * 16 + l15) * 32 + quad * 8];
        if (SPLIT) {
#pragma unroll
            for (int mi = 0; mi < 4; ++mi)
                afl[mi] = *(const short8*)&AsL[(wm + mi * 16 + l15) * 32 + quad * 8];
#pragma unroll
            for (int ni = 0; ni < 4; ++ni)
                bfl[ni] = *(const short8*)&BsL[(wn + ni * 16 + l15) * 32 + quad * 8];
        }

#pragma unroll
        for (int mi = 0; mi < 4; ++mi)
#pragma unroll
            for (int ni = 0; ni < 4; ++ni) {
                acc[mi][ni] = __builtin_amdgcn_mfma_f32_16x16x32_bf16(
                    afh[mi], bfh[ni], acc[mi][ni], 0, 0, 0);
                if (SPLIT) {
                    acc[mi][ni] = __builtin_amdgcn_mfma_f32_16x16x32_bf16(
                        afh[mi], bfl[ni], acc[mi][ni], 0, 0, 0);
                    acc[mi][ni] = __builtin_amdgcn_mfma_f32_16x16x32_bf16(
                        afl[mi], bfh[ni], acc[mi][ni], 0, 0, 0);
                }
            }
    }

#pragma unroll
    for (int mi = 0; mi < 4; ++mi)
#pragma unroll
        for (int r = 0; r < 4; ++r) {
            const int m = m0 + wm + mi * 16 + quad * 4 + r;
            float* cp = C + (size_t)m * 1024 + n0 + wn + l15;
#pragma unroll
            for (int ni = 0; ni < 4; ++ni) cp[ni * 16] = acc[mi][ni][r];
        }
}

// Fused projections: z=0 Q(split), z=1 K(split), z=2 V(plain)
__global__ __launch_bounds__(256) void proj_mfma(
    const unsigned short* __restrict__ XqH, const unsigned short* __restrict__ XqL,
    const unsigned short* __restrict__ XkH, const unsigned short* __restrict__ XkL,
    const unsigned short* __restrict__ Xv,
    const unsigned short* __restrict__ WqtH, const unsigned short* __restrict__ WqtL,
    const unsigned short* __restrict__ WktH, const unsigned short* __restrict__ WktL,
    const unsigned short* __restrict__ Wvt,
    float* __restrict__ Qc, float* __restrict__ Kc, float* __restrict__ Vc)
{
    __shared__ __align__(16) unsigned short smem[4 * 4096];
    const int m0 = blockIdx.x * 128, n0 = blockIdx.y * 128;
    if (blockIdx.z == 0)
        gemm_core<true>(smem, XqH, XqL, WqtH, WqtL, Qc, m0, n0);
    else if (blockIdx.z == 1)
        gemm_core<true>(smem, XkH, XkL, WktH, WktL, Kc, m0, n0);
    else
        gemm_core<false>(smem, Xv, nullptr, Wvt, nullptr, Vc, m0, n0);
}

__global__ __launch_bounds__(256) void out_gemm_mfma(
    const unsigned short* __restrict__ Ocb,
    const unsigned short* __restrict__ WOt,
    float* __restrict__ out)
{
    __shared__ __align__(16) unsigned short smem[2 * 4096];
    gemm_core<false>(smem, Ocb, nullptr, WOt, nullptr, out,
                     blockIdx.x * 128, blockIdx.y * 128);
}

// ---------------------------------------------------------------------------
// MFMA flash attention v6 (compile-fixed).  Round-8 structure plus:
//  - Q pre-scaled by 0.125*log2e at the split -> scores exit MFMA in base-2
//    domain; interior tiles have NO scale loop (diagonal: mask-select only)
//  - wave-uniform alpha-skip: if no row's max changed, skip o/l rescale
//  P-pack: round-8-validated per-element f2bf (RNE).
// ---------------------------------------------------------------------------
__global__ __launch_bounds__(256) void attn_mfma(const float* __restrict__ Qc,
                                                 const unsigned short* __restrict__ KHg,
                                                 const unsigned short* __restrict__ KLg,
                                                 const unsigned short* __restrict__ Vtg,
                                                 unsigned short* __restrict__ Ocb)
{
    __shared__ __align__(16) short Khi[64][72];
    __shared__ __align__(16) short Klo[64][72];
    __shared__ __align__(16) short Vts[64][72];   // [dk][key]
    __shared__ __align__(16) short Pb[4][16][72];

    const int bid = blockIdx.x;
    const int h   = bid & 15;
    const int qt  = 63 - (bid >> 4);   // longest tiles dispatch first
    const int q0  = qt * 64;

    const int t    = threadIdx.x;
    const int wave = t >> 6;
    const int lane = t & 63;
    const int quad = lane >> 4;
    const int l15  = lane & 15;

    constexpr float SCL = 0.18033688011112042f;   // 0.125 * log2(e)

    // Q A-fragments: pre-scale by SCL, then split hi/lo (once per block)
    short8 qhi[2], qlo[2];
    {
        const int qrow = q0 + wave * 16 + l15;
        const float* qp = Qc + (size_t)qrow * DMODEL + h * 64 + quad * 8;
#pragma unroll
        for (int ks = 0; ks < 2; ++ks) {
            float4 a = *(const float4*)(qp + ks * 32);
            float4 b = *(const float4*)(qp + ks * 32 + 4);
            const float xs[8] = {a.x, a.y, a.z, a.w, b.x, b.y, b.z, b.w};
#pragma unroll
            for (int j = 0; j < 8; ++j) {
                const float s = xs[j] * SCL;
                const unsigned short hi = f2bf(s);
                const unsigned short lo = f2bf(s - bf2f(hi));
                qhi[ks][j] = (short)hi;
                qlo[ks][j] = (short)lo;
            }
        }
    }

    // all-ones B fragment: B[k][0] = 1.0, other cols 0  (row-sum MFMA)
    short8 bones;
    {
        const short ob = (l15 == 0) ? (short)0x3F80 : (short)0;
#pragma unroll
        for (int j = 0; j < 8; ++j) bones[j] = ob;
    }

    float m_r[4] = {-1e30f, -1e30f, -1e30f, -1e30f};
    float4v lacc;
    float4v oacc[4];
#pragma unroll
    for (int r = 0; r < 4; ++r) lacc[r] = 0.f;
#pragma unroll
    for (int nt = 0; nt < 4; ++nt)
#pragma unroll
        for (int r = 0; r < 4; ++r) oacc[nt][r] = 0.f;

    // staging assignment: thread covers rows {srow, srow+32}, 16B col chunk
    const int srow = t >> 3;
    const int soff = (t & 7) * 8;

    // prefetch registers, initial load for jt = 0
    ushort8 kh[2], kl[2], vt[2];
#pragma unroll
    for (int i = 0; i < 2; ++i) {
        const int row = srow + 32 * i;
        kh[i] = *(const ushort8*)&KHg[(size_t)row * 1024 + h * 64 + soff];
        kl[i] = *(const ushort8*)&KLg[(size_t)row * 1024 + h * 64 + soff];
        vt[i] = *(const ushort8*)&Vtg[(size_t)(h * 64 + row) * 4096 + soff];
    }

    for (int jt = 0; jt <= qt; ++jt) {
        const int j0 = jt * 64;
        // --- stage prefetched vectors (conflict-free ds_write_b128) ---
#pragma unroll
        for (int i = 0; i < 2; ++i) {
            const int row = srow + 32 * i;
            *(ushort8*)&Khi[row][soff] = kh[i];
            *(ushort8*)&Klo[row][soff] = kl[i];
            *(ushort8*)&Vts[row][soff] = vt[i];
        }
        __syncthreads();

        // --- prefetch next tile (overlaps compute below) ---
        if (jt < qt) {
            const int jn = j0 + 64;
#pragma unroll
            for (int i = 0; i < 2; ++i) {
                const int row = srow + 32 * i;
                kh[i] = *(const ushort8*)&KHg[(size_t)(jn + row) * 1024 + h * 64 + soff];
                kl[i] = *(const ushort8*)&KLg[(size_t)(jn + row) * 1024 + h * 64 + soff];
                vt[i] = *(const ushort8*)&Vtg[(size_t)(h * 64 + row) * 4096 + jn + soff];
            }
        }

        // --- S = Q K^T, already in base-2 domain (Q pre-scaled) ---
        float4v sacc[4];
#pragma unroll
        for (int nt = 0; nt < 4; ++nt)
#pragma unroll
            for (int r = 0; r < 4; ++r) sacc[nt][r] = 0.f;
#pragma unroll
        for (int nt = 0; nt < 4; ++nt) {
            const int key = nt * 16 + l15;
#pragma unroll
            for (int ks = 0; ks < 2; ++ks) {
                const short8 bh = *(const short8*)&Khi[key][ks * 32 + quad * 8];
                const short8 bl = *(const short8*)&Klo[key][ks * 32 + quad * 8];
                sacc[nt] = __builtin_amdgcn_mfma_f32_16x16x32_bf16(qhi[ks], bh, sacc[nt], 0, 0, 0);
                sacc[nt] = __builtin_amdgcn_mfma_f32_16x16x32_bf16(qhi[ks], bl, sacc[nt], 0, 0, 0);
                sacc[nt] = __builtin_amdgcn_mfma_f32_16x16x32_bf16(qlo[ks], bh, sacc[nt], 0, 0, 0);
            }
        }

        // --- causal mask only on the diagonal tile ---
        if (jt == qt) {
#pragma unroll
            for (int nt = 0; nt < 4; ++nt) {
                const int jg = j0 + nt * 16 + l15;
#pragma unroll
                for (int r = 0; r < 4; ++r) {
                    const int qg = q0 + wave * 16 + quad * 4 + r;
                    sacc[nt][r] = (jg > qg) ? -1e9f : sacc[nt][r];
                }
            }
        }

        // --- online softmax max-path ---
        float rmax[4];
#pragma unroll
        for (int r = 0; r < 4; ++r)
            rmax[r] = fmaxf(fmaxf(sacc[0][r], sacc[1][r]), fmaxf(sacc[2][r], sacc[3][r]));
#pragma unroll
        for (int off = 1; off < 16; off <<= 1)
#pragma unroll
            for (int r = 0; r < 4; ++r)
                rmax[r] = fmaxf(rmax[r], __shfl_xor(rmax[r], off));

        float alpha[4];
#pragma unroll
        for (int r = 0; r < 4; ++r) {
            const float mn = fmaxf(m_r[r], rmax[r]);
            alpha[r] = fexp2(m_r[r] - mn);
            m_r[r] = mn;
        }

        // --- exp2 (sum folded into PV MFMA) ---
#pragma unroll
        for (int nt = 0; nt < 4; ++nt)
#pragma unroll
            for (int r = 0; r < 4; ++r)
                sacc[nt][r] = fexp2(sacc[nt][r] - m_r[r]);

        // --- rescale o/l only if some row's max changed (alpha<1) ---
        {
            const bool need = (alpha[0] < 1.f) || (alpha[1] < 1.f) ||
                              (alpha[2] < 1.f) || (alpha[3] < 1.f);
            if (__any(need ? 1 : 0)) {
#pragma unroll
                for (int r = 0; r < 4; ++r) lacc[r] *= alpha[r];
#pragma unroll
                for (int nt = 0; nt < 4; ++nt)
#pragma unroll
                    for (int r = 0; r < 4; ++r)
                        oacc[nt][r] *= alpha[r];
            }
        }

        // --- P (C-layout) -> per-wave LDS strip -> A-layout (f2bf, RNE) ---
#pragma unroll
        for (int nt = 0; nt < 4; ++nt)
#pragma unroll
            for (int r = 0; r < 4; ++r)
                Pb[wave][quad * 4 + r][nt * 16 + l15] = (short)f2bf(sacc[nt][r]);
        __asm__ volatile("s_waitcnt lgkmcnt(0)" ::: "memory");

        // --- O += P @ V, and l += P @ 1 ---
        short8 af[2];
        af[0] = *(const short8*)&Pb[wave][l15][quad * 8];
        af[1] = *(const short8*)&Pb[wave][l15][32 + quad * 8];
#pragma unroll
        for (int nt = 0; nt < 4; ++nt) {
            const int dk = nt * 16 + l15;
#pragma unroll
            for (int ks = 0; ks < 2; ++ks) {
                const short8 bv = *(const short8*)&Vts[dk][ks * 32 + quad * 8];
                oacc[nt] = __builtin_amdgcn_mfma_f32_16x16x32_bf16(af[ks], bv, oacc[nt], 0, 0, 0);
            }
        }
        lacc = __builtin_amdgcn_mfma_f32_16x16x32_bf16(af[0], bones, lacc, 0, 0, 0);
        lacc = __builtin_amdgcn_mfma_f32_16x16x32_bf16(af[1], bones, lacc, 0, 0, 0);
        __syncthreads();   // LDS tiles free before restaging
    }

    // --- epilogue: broadcast l from col-0 lanes, normalize, write bf16 ---
#pragma unroll
    for (int r = 0; r < 4; ++r) {
        const float lsum = __shfl(lacc[r], (lane & 48));   // lane quad*16 (l15==0)
        const float inv  = 1.0f / lsum;
        const int qg = q0 + wave * 16 + quad * 4 + r;
        unsigned short* op = Ocb + (size_t)qg * DMODEL + h * 64 + l15;
#pragma unroll
        for (int nt = 0; nt < 4; ++nt)
            op[nt * 16] = f2bf(oacc[nt][r] * inv);
    }
}

extern "C" void kernel_launch(void* const* d_in, const int* in_sizes, int n_in,
                              void* d_out, int out_size, void* d_ws, size_t ws_size,
                              hipStream_t stream)
{
    const float* Q  = (const float*)d_in[0];
    const float* K  = (const float*)d_in[1];
    const float* V  = (const float*)d_in[2];
    const float* WQ = (const float*)d_in[3];
    const float* WK = (const float*)d_in[4];
    const float* WV = (const float*)d_in[5];
    const float* WO = (const float*)d_in[6];

    float* out = (float*)d_out;

    // Workspace carve-up (108 MB, same as validated rounds 3/5/7/8)
    const size_t SD4 = (size_t)S * DMODEL * 4;       // fp32 S x D  (16 MB)
    const size_t SD2 = (size_t)S * DMODEL * 2;       // bf16 S x D  ( 8 MB)
    const size_t W2  = (size_t)DMODEL * DMODEL * 2;  // bf16 D x D  ( 2 MB)
    char* p = (char*)d_ws;
    auto take = [&](size_t b) { char* r = p; p += b; return r; };

    float* Qc = (float*)take(SD4);
    float* Kc = (float*)take(SD4);
    float* Vc = (float*)take(SD4);
    unsigned short* XqH = (unsigned short*)take(SD2);
    unsigned short* XqL = (unsigned short*)take(SD2);
    unsigned short* XkH = (unsigned short*)take(SD2);
    unsigned short* XkL = (unsigned short*)take(SD2);
    unsigned short* Xv  = (unsigned short*)take(SD2);
    unsigned short* WqtH = (unsigned short*)take(W2);
    unsigned short* WqtL = (unsigned short*)take(W2);
    unsigned short* WktH = (unsigned short*)take(W2);
    unsigned short* WktL = (unsigned short*)take(W2);
    unsigned short* Wvt  = (unsigned short*)take(W2);
    unsigned short* WOt  = (unsigned short*)take(W2);
    unsigned short* Ocb  = (unsigned short*)take(SD2);
    // Aliases: XqH/XqL/Xv are dead after proj_mfma (stream-serialized).
    unsigned short* KHg = XqH;
    unsigned short* KLg = XqL;
    unsigned short* Vtg = Xv;

    // 1) input splits (Q,K hi/lo; V bf16)
    split_inputs<<<dim3(2048, 1, 3), 256, 0, stream>>>(Q, K, V,
                                                       XqH, XqL, XkH, XkL, Xv);
    // 2) all weight transposes in one launch
    transpose_w_all<<<dim3(16, 1, 64), 256, 0, stream>>>(
        WQ, WK, WV, WO, WqtH, WqtL, WktH, WktL, Wvt, WOt);
    // 3) projections (DMA-staged GEMM): fp32 Qc, Kc, Vc
    proj_mfma<<<dim3(S / 128, DMODEL / 128, 3), 256, 0, stream>>>(
        XqH, XqL, XkH, XkL, Xv, WqtH, WqtL, WktH, WktL, Wvt, Qc, Kc, Vc);
    // 4) pre-split K and pre-transpose V (validated)
    conv_k<<<dim3(2048), 256, 0, stream>>>(Kc, KHg, KLg);
    transpose_v<<<dim3(S / 64, DMODEL / 64), 256, 0, stream>>>(Vc, Vtg);
    // 5) causal flash attention -> bf16 Ocb
    attn_mfma<<<dim3((S / 64) * H), 256, 0, stream>>>(Qc, KHg, KLg, Vtg, Ocb);
    // 6) output projection (DMA-staged GEMM)
    out_gemm_mfma<<<dim3(S / 128, DMODEL / 128), 256, 0, stream>>>(Ocb, WOt, out);
}

// Round 11
// 360.812 us; speedup vs baseline: 1.0043x; 1.0043x over previous
//
#include <hip/hip_runtime.h>
#include <hip/hip_bf16.h>

// Problem constants
constexpr int S      = 4096;
constexpr int DMODEL = 1024;
constexpr int H      = 16;
constexpr int DK     = 64;

typedef __attribute__((ext_vector_type(8))) short          short8;
typedef __attribute__((ext_vector_type(4))) short          short4v;
typedef __attribute__((ext_vector_type(4))) float          float4v;
typedef __attribute__((ext_vector_type(4))) unsigned short ushort4v;
typedef __attribute__((ext_vector_type(8))) unsigned short ushort8;

// RNE float -> bf16 (bit pattern), and back
__device__ __forceinline__ unsigned short f2bf(float x) {
    unsigned u = __builtin_bit_cast(unsigned, x);
    u += 0x7FFFu + ((u >> 16) & 1u);
    return (unsigned short)(u >> 16);
}
__device__ __forceinline__ float bf2f(unsigned short h) {
    unsigned u = ((unsigned)h) << 16;
    return __builtin_bit_cast(float, u);
}
__device__ __forceinline__ float fexp2(float x) { return __builtin_amdgcn_exp2f(x); }

// async global->LDS DMA, 16B per lane; lds dest = wave-uniform base + lane*16
__device__ __forceinline__ void gl_lds16(const unsigned short* g, unsigned short* l) {
    __builtin_amdgcn_global_load_lds(
        (const __attribute__((address_space(1))) unsigned int*)g,
        (__attribute__((address_space(3))) unsigned int*)l, 16, 0, 0);
}

// ---------------------------------------------------------------------------
// Prep 1: elementwise split of X inputs (round-3 exact).
// ---------------------------------------------------------------------------
__global__ __launch_bounds__(256) void split_inputs(const float* __restrict__ Q,
                                                    const float* __restrict__ K,
                                                    const float* __restrict__ V,
                                                    unsigned short* __restrict__ QH,
                                                    unsigned short* __restrict__ QL,
                                                    unsigned short* __restrict__ KH,
                                                    unsigned short* __restrict__ KL,
                                                    unsigned short* __restrict__ Vb)
{
    const int z = blockIdx.z;
    const size_t base = ((size_t)blockIdx.x * 256 + threadIdx.x) * 8;
    const float* src = (z == 0) ? Q : (z == 1) ? K : V;
    const float4 a = *(const float4*)(src + base);
    const float4 b = *(const float4*)(src + base + 4);
    const float xs[8] = {a.x, a.y, a.z, a.w, b.x, b.y, b.z, b.w};
    ushort8 hv, lv;
#pragma unroll
    for (int j = 0; j < 8; ++j) {
        const unsigned short h = f2bf(xs[j]);
        hv[j] = h;
        lv[j] = f2bf(xs[j] - bf2f(h));
    }
    if (z == 0)      { *(ushort8*)(QH + base) = hv; *(ushort8*)(QL + base) = lv; }
    else if (z == 1) { *(ushort8*)(KH + base) = hv; *(ushort8*)(KL + base) = lv; }
    else             { *(ushort8*)(Vb + base) = hv; }
}

// ---------------------------------------------------------------------------
// Elementwise split of fp32 Kc -> bf16 hi/lo (round-5 validated).
// ---------------------------------------------------------------------------
__global__ __launch_bounds__(256) void conv_k(const float* __restrict__ Kc,
                                              unsigned short* __restrict__ KH,
                                              unsigned short* __restrict__ KL)
{
    const size_t base = ((size_t)blockIdx.x * 256 + threadIdx.x) * 8;
    const float4 a = *(const float4*)(Kc + base);
    const float4 b = *(const float4*)(Kc + base + 4);
    const float xs[8] = {a.x, a.y, a.z, a.w, b.x, b.y, b.z, b.w};
    ushort8 hv, lv;
#pragma unroll
    for (int j = 0; j < 8; ++j) {
        const unsigned short h = f2bf(xs[j]);
        hv[j] = h;
        lv[j] = f2bf(xs[j] - bf2f(h));
    }
    *(ushort8*)(KH + base) = hv;
    *(ushort8*)(KL + base) = lv;
}

// ---------------------------------------------------------------------------
// Transpose fp32 Vc [s][1024] -> bf16 Vt [n][4096] (round-7 validated).
// ---------------------------------------------------------------------------
__global__ __launch_bounds__(256) void transpose_v(const float* __restrict__ Vc,
                                                   unsigned short* __restrict__ Vt)
{
    __shared__ unsigned short Ts[64][68];
    const int t  = threadIdx.x;
    const int s0 = blockIdx.x * 64;
    const int n0 = blockIdx.y * 64;
#pragma unroll
    for (int i = 0; i < 4; ++i) {
        const int row = (t >> 4) + i * 16;     // s index
        const int col = (t & 15) * 4;          // n index
        const float4 v = *(const float4*)&Vc[(size_t)(s0 + row) * 1024 + n0 + col];
        Ts[row][col + 0] = f2bf(v.x); Ts[row][col + 1] = f2bf(v.y);
        Ts[row][col + 2] = f2bf(v.z); Ts[row][col + 3] = f2bf(v.w);
    }
    __syncthreads();
#pragma unroll
    for (int i = 0; i < 4; ++i) {
        const int n  = (t >> 4) + i * 16;      // out row (n)
        const int sb = (t & 15) * 4;           // out col (s)
        ushort4v v;
#pragma unroll
        for (int j = 0; j < 4; ++j) v[j] = Ts[sb + j][n];
        *(ushort4v*)&Vt[(size_t)(n0 + n) * 4096 + s0 + sb] = v;
    }
}

// ---------------------------------------------------------------------------
// Prep 2: all four weight transposes fused into one launch (round-10).
// blockIdx.z: z>>4 selects matrix (0=WQ,1=WK,2=WV,3=WO), z&15 = slab.
// ---------------------------------------------------------------------------
__global__ __launch_bounds__(256) void transpose_w_all(
    const float* __restrict__ WQ, const float* __restrict__ WK,
    const float* __restrict__ WV, const float* __restrict__ WO,
    unsigned short* __restrict__ WqtH, unsigned short* __restrict__ WqtL,
    unsigned short* __restrict__ WktH, unsigned short* __restrict__ WktL,
    unsigned short* __restrict__ Wvt,  unsigned short* __restrict__ WOt)
{
    __shared__ float Ts[64][65];
    const int t     = threadIdx.x;
    const int which = blockIdx.z >> 4;
    const int z     = blockIdx.z & 15;
    const int r0    = blockIdx.x * 64;

    const float* in;
    unsigned short *oh, *ol;
    int z_mult, rstride;
    if (which == 0)      { in = WQ; oh = WqtH; ol = WqtL; z_mult = 65536; rstride = 64; }
    else if (which == 1) { in = WK; oh = WktH; ol = WktL; z_mult = 65536; rstride = 64; }
    else if (which == 2) { in = WV; oh = Wvt;  ol = nullptr; z_mult = 65536; rstride = 64; }
    else                 { in = WO; oh = WOt;  ol = nullptr; z_mult = 64;    rstride = 1024; }

    const float* src = in + (size_t)z * z_mult;
#pragma unroll
    for (int i = 0; i < 4; ++i) {
        const int row = (t >> 4) + i * 16;
        const int col = (t & 15) * 4;
        const float4 v = *(const float4*)&src[(size_t)(r0 + row) * rstride + col];
        Ts[row][col + 0] = v.x; Ts[row][col + 1] = v.y;
        Ts[row][col + 2] = v.z; Ts[row][col + 3] = v.w;
    }
    __syncthreads();
#pragma unroll
    for (int i = 0; i < 4; ++i) {
        const int c  = (t >> 4) + i * 16;
        const int rb = (t & 15) * 4;
        ushort4v hv, lv;
#pragma unroll
        for (int j = 0; j < 4; ++j) {
            const float x = Ts[rb + j][c];
            const unsigned short h = f2bf(x);
            hv[j] = h;
            lv[j] = f2bf(x - bf2f(h));
        }
        const size_t o = (size_t)(z * 64 + c) * 1024 + r0 + rb;
        *(ushort4v*)&oh[o] = hv;
        if (ol) *(ushort4v*)&ol[o] = lv;
    }
}

// ---------------------------------------------------------------------------
// bf16 MFMA GEMM core (round-8: global_load_lds width=16 staging).
// ---------------------------------------------------------------------------
template <bool SPLIT>
__device__ __forceinline__ void gemm_core(unsigned short* __restrict__ sm,
                                          const unsigned short* __restrict__ Ah,
                                          const unsigned short* __restrict__ Al,
                                          const unsigned short* __restrict__ Bh,
                                          const unsigned short* __restrict__ Bl,
                                          float* __restrict__ C,
                                          int m0, int n0)
{
    unsigned short* AsH = sm;            // [128][32]
    unsigned short* BsH = sm + 4096;
    unsigned short* AsL = sm + 8192;     // SPLIT only
    unsigned short* BsL = sm + 12288;

    const int t    = threadIdx.x;
    const int wave = t >> 6;
    const int lane = t & 63;
    const int quad = lane >> 4;
    const int l15  = lane & 15;
    const int wm   = (wave & 1) * 64;
    const int wn   = (wave >> 1) * 64;

    float4v acc[4][4];
#pragma unroll
    for (int mi = 0; mi < 4; ++mi)
#pragma unroll
        for (int ni = 0; ni < 4; ++ni)
#pragma unroll
            for (int r = 0; r < 4; ++r) acc[mi][ni][r] = 0.f;

    for (int k0 = 0; k0 < 1024; k0 += 32) {
        __syncthreads();   // prior iteration's LDS reads complete
#pragma unroll
        for (int i = 0; i < 2; ++i) {
            const int c   = t + 256 * i;
            const int row = c >> 2;
            const int kc  = (c & 3) * 8;
            const int lb  = (i * 256 + wave * 64) * 8;   // wave-uniform base (shorts)
            gl_lds16(&Ah[(size_t)(m0 + row) * 1024 + k0 + kc], AsH + lb);
            gl_lds16(&Bh[(size_t)(n0 + row) * 1024 + k0 + kc], BsH + lb);
            if (SPLIT) {
                gl_lds16(&Al[(size_t)(m0 + row) * 1024 + k0 + kc], AsL + lb);
                gl_lds16(&Bl[(size_t)(n0 + row) * 1024 + k0 + kc], BsL + lb);
            }
        }
        __syncthreads();   // vmcnt drained before barrier -> data visible

        short8 afh[4], bfh[4], afl[4], bfl[4];
#pragma unroll
        for (int mi = 0; mi < 4; ++mi)
            afh[mi] = *(const short8*)&AsH[(wm + mi * 16 + l15) * 32 + quad * 8];
#pragma unroll
        for (int ni = 0; ni < 4; ++ni)
            bfh[ni] = *(const short8*)&BsH[(wn + ni * 16 + l15) * 32 + quad * 8];
        if (SPLIT) {
#pragma unroll
            for (int mi = 0; mi < 4; ++mi)
                afl[mi] = *(const short8*)&AsL[(wm + mi * 16 + l15) * 32 + quad * 8];
#pragma unroll
            for (int ni = 0; ni < 4; ++ni)
                bfl[ni] = *(const short8*)&BsL[(wn + ni * 16 + l15) * 32 + quad * 8];
        }

#pragma unroll
        for (int mi = 0; mi < 4; ++mi)
#pragma unroll
            for (int ni = 0; ni < 4; ++ni) {
                acc[mi][ni] = __builtin_amdgcn_mfma_f32_16x16x32_bf16(
                    afh[mi], bfh[ni], acc[mi][ni], 0, 0, 0);
                if (SPLIT) {
                    acc[mi][ni] = __builtin_amdgcn_mfma_f32_16x16x32_bf16(
                        afh[mi], bfl[ni], acc[mi][ni], 0, 0, 0);
                    acc[mi][ni] = __builtin_amdgcn_mfma_f32_16x16x32_bf16(
                        afl[mi], bfh[ni], acc[mi][ni], 0, 0, 0);
                }
            }
    }

#pragma unroll
    for (int mi = 0; mi < 4; ++mi)
#pragma unroll
        for (int r = 0; r < 4; ++r) {
            const int m = m0 + wm + mi * 16 + quad * 4 + r;
            float* cp = C + (size_t)m * 1024 + n0 + wn + l15;
#pragma unroll
            for (int ni = 0; ni < 4; ++ni) cp[ni * 16] = acc[mi][ni][r];
        }
}

// Fused projections: z=0 Q(split), z=1 K(split), z=2 V(plain)
__global__ __launch_bounds__(256) void proj_mfma(
    const unsigned short* __restrict__ XqH, const unsigned short* __restrict__ XqL,
    const unsigned short* __restrict__ XkH, const unsigned short* __restrict__ XkL,
    const unsigned short* __restrict__ Xv,
    const unsigned short* __restrict__ WqtH, const unsigned short* __restrict__ WqtL,
    const unsigned short* __restrict__ WktH, const unsigned short* __restrict__ WktL,
    const unsigned short* __restrict__ Wvt,
    float* __restrict__ Qc, float* __restrict__ Kc, float* __restrict__ Vc)
{
    __shared__ __align__(16) unsigned short smem[4 * 4096];
    const int m0 = blockIdx.x * 128, n0 = blockIdx.y * 128;
    if (blockIdx.z == 0)
        gemm_core<true>(smem, XqH, XqL, WqtH, WqtL, Qc, m0, n0);
    else if (blockIdx.z == 1)
        gemm_core<true>(smem, XkH, XkL, WktH, WktL, Kc, m0, n0);
    else
        gemm_core<false>(smem, Xv, nullptr, Wvt, nullptr, Vc, m0, n0);
}

__global__ __launch_bounds__(256) void out_gemm_mfma(
    const unsigned short* __restrict__ Ocb,
    const unsigned short* __restrict__ WOt,
    float* __restrict__ out)
{
    __shared__ __align__(16) unsigned short smem[2 * 4096];
    gemm_core<false>(smem, Ocb, nullptr, WOt, nullptr, out,
                     blockIdx.x * 128, blockIdx.y * 128);
}

// ---------------------------------------------------------------------------
// MFMA flash attention v7.  Round-8 structure plus the two validated-direction
// VALU trims (Q pre-scaled into base-2 domain; diagonal-only mask), WITHOUT
// round-10's alpha-skip branch (VGPR 76->92, occupancy 29.8->20.1, regressed).
// Unconditional alpha rescale restored.
// ---------------------------------------------------------------------------
__global__ __launch_bounds__(256) void attn_mfma(const float* __restrict__ Qc,
                                                 const unsigned short* __restrict__ KHg,
                                                 const unsigned short* __restrict__ KLg,
                                                 const unsigned short* __restrict__ Vtg,
                                                 unsigned short* __restrict__ Ocb)
{
    __shared__ __align__(16) short Khi[64][72];
    __shared__ __align__(16) short Klo[64][72];
    __shared__ __align__(16) short Vts[64][72];   // [dk][key]
    __shared__ __align__(16) short Pb[4][16][72];

    const int bid = blockIdx.x;
    const int h   = bid & 15;
    const int qt  = 63 - (bid >> 4);   // longest tiles dispatch first
    const int q0  = qt * 64;

    const int t    = threadIdx.x;
    const int wave = t >> 6;
    const int lane = t & 63;
    const int quad = lane >> 4;
    const int l15  = lane & 15;

    constexpr float SCL = 0.18033688011112042f;   // 0.125 * log2(e)

    // Q A-fragments: pre-scale by SCL, then split hi/lo (once per block)
    short8 qhi[2], qlo[2];
    {
        const int qrow = q0 + wave * 16 + l15;
        const float* qp = Qc + (size_t)qrow * DMODEL + h * 64 + quad * 8;
#pragma unroll
        for (int ks = 0; ks < 2; ++ks) {
            float4 a = *(const float4*)(qp + ks * 32);
            float4 b = *(const float4*)(qp + ks * 32 + 4);
            const float xs[8] = {a.x, a.y, a.z, a.w, b.x, b.y, b.z, b.w};
#pragma unroll
            for (int j = 0; j < 8; ++j) {
                const float s = xs[j] * SCL;
                const unsigned short hi = f2bf(s);
                const unsigned short lo = f2bf(s - bf2f(hi));
                qhi[ks][j] = (short)hi;
                qlo[ks][j] = (short)lo;
            }
        }
    }

    // all-ones B fragment: B[k][0] = 1.0, other cols 0  (row-sum MFMA)
    short8 bones;
    {
        const short ob = (l15 == 0) ? (short)0x3F80 : (short)0;
#pragma unroll
        for (int j = 0; j < 8; ++j) bones[j] = ob;
    }

    float m_r[4] = {-1e30f, -1e30f, -1e30f, -1e30f};
    float4v lacc;
    float4v oacc[4];
#pragma unroll
    for (int r = 0; r < 4; ++r) lacc[r] = 0.f;
#pragma unroll
    for (int nt = 0; nt < 4; ++nt)
#pragma unroll
        for (int r = 0; r < 4; ++r) oacc[nt][r] = 0.f;

    // staging assignment: thread covers rows {srow, srow+32}, 16B col chunk
    const int srow = t >> 3;
    const int soff = (t & 7) * 8;

    // prefetch registers, initial load for jt = 0
    ushort8 kh[2], kl[2], vt[2];
#pragma unroll
    for (int i = 0; i < 2; ++i) {
        const int row = srow + 32 * i;
        kh[i] = *(const ushort8*)&KHg[(size_t)row * 1024 + h * 64 + soff];
        kl[i] = *(const ushort8*)&KLg[(size_t)row * 1024 + h * 64 + soff];
        vt[i] = *(const ushort8*)&Vtg[(size_t)(h * 64 + row) * 4096 + soff];
    }

    for (int jt = 0; jt <= qt; ++jt) {
        const int j0 = jt * 64;
        // --- stage prefetched vectors (conflict-free ds_write_b128) ---
#pragma unroll
        for (int i = 0; i < 2; ++i) {
            const int row = srow + 32 * i;
            *(ushort8*)&Khi[row][soff] = kh[i];
            *(ushort8*)&Klo[row][soff] = kl[i];
            *(ushort8*)&Vts[row][soff] = vt[i];
        }
        __syncthreads();

        // --- prefetch next tile (overlaps compute below) ---
        if (jt < qt) {
            const int jn = j0 + 64;
#pragma unroll
            for (int i = 0; i < 2; ++i) {
                const int row = srow + 32 * i;
                kh[i] = *(const ushort8*)&KHg[(size_t)(jn + row) * 1024 + h * 64 + soff];
                kl[i] = *(const ushort8*)&KLg[(size_t)(jn + row) * 1024 + h * 64 + soff];
                vt[i] = *(const ushort8*)&Vtg[(size_t)(h * 64 + row) * 4096 + jn + soff];
            }
        }

        // --- S = Q K^T, already in base-2 domain (Q pre-scaled) ---
        float4v sacc[4];
#pragma unroll
        for (int nt = 0; nt < 4; ++nt)
#pragma unroll
            for (int r = 0; r < 4; ++r) sacc[nt][r] = 0.f;
#pragma unroll
        for (int nt = 0; nt < 4; ++nt) {
            const int key = nt * 16 + l15;
#pragma unroll
            for (int ks = 0; ks < 2; ++ks) {
                const short8 bh = *(const short8*)&Khi[key][ks * 32 + quad * 8];
                const short8 bl = *(const short8*)&Klo[key][ks * 32 + quad * 8];
                sacc[nt] = __builtin_amdgcn_mfma_f32_16x16x32_bf16(qhi[ks], bh, sacc[nt], 0, 0, 0);
                sacc[nt] = __builtin_amdgcn_mfma_f32_16x16x32_bf16(qhi[ks], bl, sacc[nt], 0, 0, 0);
                sacc[nt] = __builtin_amdgcn_mfma_f32_16x16x32_bf16(qlo[ks], bh, sacc[nt], 0, 0, 0);
            }
        }

        // --- causal mask only on the diagonal tile ---
        if (jt == qt) {
#pragma unroll
            for (int nt = 0; nt < 4; ++nt) {
                const int jg = j0 + nt * 16 + l15;
#pragma unroll
                for (int r = 0; r < 4; ++r) {
                    const int qg = q0 + wave * 16 + quad * 4 + r;
                    sacc[nt][r] = (jg > qg) ? -1e9f : sacc[nt][r];
                }
            }
        }

        // --- online softmax max-path ---
        float rmax[4];
#pragma unroll
        for (int r = 0; r < 4; ++r)
            rmax[r] = fmaxf(fmaxf(sacc[0][r], sacc[1][r]), fmaxf(sacc[2][r], sacc[3][r]));
#pragma unroll
        for (int off = 1; off < 16; off <<= 1)
#pragma unroll
            for (int r = 0; r < 4; ++r)
                rmax[r] = fmaxf(rmax[r], __shfl_xor(rmax[r], off));

        float alpha[4];
#pragma unroll
        for (int r = 0; r < 4; ++r) {
            const float mn = fmaxf(m_r[r], rmax[r]);
            alpha[r] = fexp2(m_r[r] - mn);
            m_r[r] = mn;
        }

        // --- exp2 (sum folded into PV MFMA) ---
#pragma unroll
        for (int nt = 0; nt < 4; ++nt)
#pragma unroll
            for (int r = 0; r < 4; ++r)
                sacc[nt][r] = fexp2(sacc[nt][r] - m_r[r]);

        // --- unconditional rescale (round-8 validated; branch regressed r10) ---
#pragma unroll
        for (int r = 0; r < 4; ++r) lacc[r] *= alpha[r];
#pragma unroll
        for (int nt = 0; nt < 4; ++nt)
#pragma unroll
            for (int r = 0; r < 4; ++r)
                oacc[nt][r] *= alpha[r];

        // --- P (C-layout) -> per-wave LDS strip -> A-layout (f2bf, RNE) ---
#pragma unroll
        for (int nt = 0; nt < 4; ++nt)
#pragma unroll
            for (int r = 0; r < 4; ++r)
                Pb[wave][quad * 4 + r][nt * 16 + l15] = (short)f2bf(sacc[nt][r]);
        __asm__ volatile("s_waitcnt lgkmcnt(0)" ::: "memory");

        // --- O += P @ V, and l += P @ 1 ---
        short8 af[2];
        af[0] = *(const short8*)&Pb[wave][l15][quad * 8];
        af[1] = *(const short8*)&Pb[wave][l15][32 + quad * 8];
#pragma unroll
        for (int nt = 0; nt < 4; ++nt) {
            const int dk = nt * 16 + l15;
#pragma unroll
            for (int ks = 0; ks < 2; ++ks) {
                const short8 bv = *(const short8*)&Vts[dk][ks * 32 + quad * 8];
                oacc[nt] = __builtin_amdgcn_mfma_f32_16x16x32_bf16(af[ks], bv, oacc[nt], 0, 0, 0);
            }
        }
        lacc = __builtin_amdgcn_mfma_f32_16x16x32_bf16(af[0], bones, lacc, 0, 0, 0);
        lacc = __builtin_amdgcn_mfma_f32_16x16x32_bf16(af[1], bones, lacc, 0, 0, 0);
        __syncthreads();   // LDS tiles free before restaging
    }

    // --- epilogue: broadcast l from col-0 lanes, normalize, write bf16 ---
#pragma unroll
    for (int r = 0; r < 4; ++r) {
        const float lsum = __shfl(lacc[r], (lane & 48));   // lane quad*16 (l15==0)
        const float inv  = 1.0f / lsum;
        const int qg = q0 + wave * 16 + quad * 4 + r;
        unsigned short* op = Ocb + (size_t)qg * DMODEL + h * 64 + l15;
#pragma unroll
        for (int nt = 0; nt < 4; ++nt)
            op[nt * 16] = f2bf(oacc[nt][r] * inv);
    }
}

extern "C" void kernel_launch(void* const* d_in, const int* in_sizes, int n_in,
                              void* d_out, int out_size, void* d_ws, size_t ws_size,
                              hipStream_t stream)
{
    const float* Q  = (const float*)d_in[0];
    const float* K  = (const float*)d_in[1];
    const float* V  = (const float*)d_in[2];
    const float* WQ = (const float*)d_in[3];
    const float* WK = (const float*)d_in[4];
    const float* WV = (const float*)d_in[5];
    const float* WO = (const float*)d_in[6];

    float* out = (float*)d_out;

    // Workspace carve-up (108 MB, same as validated rounds 3/5/7/8)
    const size_t SD4 = (size_t)S * DMODEL * 4;       // fp32 S x D  (16 MB)
    const size_t SD2 = (size_t)S * DMODEL * 2;       // bf16 S x D  ( 8 MB)
    const size_t W2  = (size_t)DMODEL * DMODEL * 2;  // bf16 D x D  ( 2 MB)
    char* p = (char*)d_ws;
    auto take = [&](size_t b) { char* r = p; p += b; return r; };

    float* Qc = (float*)take(SD4);
    float* Kc = (float*)take(SD4);
    float* Vc = (float*)take(SD4);
    unsigned short* XqH = (unsigned short*)take(SD2);
    unsigned short* XqL = (unsigned short*)take(SD2);
    unsigned short* XkH = (unsigned short*)take(SD2);
    unsigned short* XkL = (unsigned short*)take(SD2);
    unsigned short* Xv  = (unsigned short*)take(SD2);
    unsigned short* WqtH = (unsigned short*)take(W2);
    unsigned short* WqtL = (unsigned short*)take(W2);
    unsigned short* WktH = (unsigned short*)take(W2);
    unsigned short* WktL = (unsigned short*)take(W2);
    unsigned short* Wvt  = (unsigned short*)take(W2);
    unsigned short* WOt  = (unsigned short*)take(W2);
    unsigned short* Ocb  = (unsigned short*)take(SD2);
    // Aliases: XqH/XqL/Xv are dead after proj_mfma (stream-serialized).
    unsigned short* KHg = XqH;
    unsigned short* KLg = XqL;
    unsigned short* Vtg = Xv;

    // 1) input splits (Q,K hi/lo; V bf16)
    split_inputs<<<dim3(2048, 1, 3), 256, 0, stream>>>(Q, K, V,
                                                       XqH, XqL, XkH, XkL, Xv);
    // 2) all weight transposes in one launch
    transpose_w_all<<<dim3(16, 1, 64), 256, 0, stream>>>(
        WQ, WK, WV, WO, WqtH, WqtL, WktH, WktL, Wvt, WOt);
    // 3) projections (DMA-staged GEMM): fp32 Qc, Kc, Vc
    proj_mfma<<<dim3(S / 128, DMODEL / 128, 3), 256, 0, stream>>>(
        XqH, XqL, XkH, XkL, Xv, WqtH, WqtL, WktH, WktL, Wvt, Qc, Kc, Vc);
    // 4) pre-split K and pre-transpose V (validated)
    conv_k<<<dim3(2048), 256, 0, stream>>>(Kc, KHg, KLg);
    transpose_v<<<dim3(S / 64, DMODEL / 64), 256, 0, stream>>>(Vc, Vtg);
    // 5) causal flash attention -> bf16 Ocb
    attn_mfma<<<dim3((S / 64) * H), 256, 0, stream>>>(Qc, KHg, KLg, Vtg, Ocb);
    // 6) output projection (DMA-staged GEMM)
    out_gemm_mfma<<<dim3(S / 128, DMODEL / 128), 256, 0, stream>>>(Ocb, WOt, out);
}

// Round 12
// 337.853 us; speedup vs baseline: 1.0726x; 1.0680x over previous
//
#include <hip/hip_runtime.h>
#include <hip/hip_bf16.h>

// Problem constants
constexpr int S      = 4096;
constexpr int DMODEL = 1024;
constexpr int H      = 16;
constexpr int DK     = 64;

typedef __attribute__((ext_vector_type(8))) short          short8;
typedef __attribute__((ext_vector_type(4))) short          short4v;
typedef __attribute__((ext_vector_type(4))) float          float4v;
typedef __attribute__((ext_vector_type(4))) unsigned short ushort4v;
typedef __attribute__((ext_vector_type(8))) unsigned short ushort8;

// RNE float -> bf16 (bit pattern), and back
__device__ __forceinline__ unsigned short f2bf(float x) {
    unsigned u = __builtin_bit_cast(unsigned, x);
    u += 0x7FFFu + ((u >> 16) & 1u);
    return (unsigned short)(u >> 16);
}
__device__ __forceinline__ float bf2f(unsigned short h) {
    unsigned u = ((unsigned)h) << 16;
    return __builtin_bit_cast(float, u);
}
__device__ __forceinline__ float fexp2(float x) { return __builtin_amdgcn_exp2f(x); }

// async global->LDS DMA, 16B per lane; lds dest = wave-uniform base + lane*16
__device__ __forceinline__ void gl_lds16(const unsigned short* g, unsigned short* l) {
    __builtin_amdgcn_global_load_lds(
        (const __attribute__((address_space(1))) unsigned int*)g,
        (__attribute__((address_space(3))) unsigned int*)l, 16, 0, 0);
}

// ---------------------------------------------------------------------------
// Prep 1: elementwise split of X inputs (round-3 exact).
// ---------------------------------------------------------------------------
__global__ __launch_bounds__(256) void split_inputs(const float* __restrict__ Q,
                                                    const float* __restrict__ K,
                                                    const float* __restrict__ V,
                                                    unsigned short* __restrict__ QH,
                                                    unsigned short* __restrict__ QL,
                                                    unsigned short* __restrict__ KH,
                                                    unsigned short* __restrict__ KL,
                                                    unsigned short* __restrict__ Vb)
{
    const int z = blockIdx.z;
    const size_t base = ((size_t)blockIdx.x * 256 + threadIdx.x) * 8;
    const float* src = (z == 0) ? Q : (z == 1) ? K : V;
    const float4 a = *(const float4*)(src + base);
    const float4 b = *(const float4*)(src + base + 4);
    const float xs[8] = {a.x, a.y, a.z, a.w, b.x, b.y, b.z, b.w};
    ushort8 hv, lv;
#pragma unroll
    for (int j = 0; j < 8; ++j) {
        const unsigned short h = f2bf(xs[j]);
        hv[j] = h;
        lv[j] = f2bf(xs[j] - bf2f(h));
    }
    if (z == 0)      { *(ushort8*)(QH + base) = hv; *(ushort8*)(QL + base) = lv; }
    else if (z == 1) { *(ushort8*)(KH + base) = hv; *(ushort8*)(KL + base) = lv; }
    else             { *(ushort8*)(Vb + base) = hv; }
}

// ---------------------------------------------------------------------------
// Transpose fp32 Vc [s][1024] -> bf16 Vt [n][4096] (round-7 validated).
// ---------------------------------------------------------------------------
__global__ __launch_bounds__(256) void transpose_v(const float* __restrict__ Vc,
                                                   unsigned short* __restrict__ Vt)
{
    __shared__ unsigned short Ts[64][68];
    const int t  = threadIdx.x;
    const int s0 = blockIdx.x * 64;
    const int n0 = blockIdx.y * 64;
#pragma unroll
    for (int i = 0; i < 4; ++i) {
        const int row = (t >> 4) + i * 16;     // s index
        const int col = (t & 15) * 4;          // n index
        const float4 v = *(const float4*)&Vc[(size_t)(s0 + row) * 1024 + n0 + col];
        Ts[row][col + 0] = f2bf(v.x); Ts[row][col + 1] = f2bf(v.y);
        Ts[row][col + 2] = f2bf(v.z); Ts[row][col + 3] = f2bf(v.w);
    }
    __syncthreads();
#pragma unroll
    for (int i = 0; i < 4; ++i) {
        const int n  = (t >> 4) + i * 16;      // out row (n)
        const int sb = (t & 15) * 4;           // out col (s)
        ushort4v v;
#pragma unroll
        for (int j = 0; j < 4; ++j) v[j] = Ts[sb + j][n];
        *(ushort4v*)&Vt[(size_t)(n0 + n) * 4096 + s0 + sb] = v;
    }
}

// ---------------------------------------------------------------------------
// Prep 2: all four weight transposes fused into one launch (round-10/11
// validated, saved ~9 µs of launch gaps).
// ---------------------------------------------------------------------------
__global__ __launch_bounds__(256) void transpose_w_all(
    const float* __restrict__ WQ, const float* __restrict__ WK,
    const float* __restrict__ WV, const float* __restrict__ WO,
    unsigned short* __restrict__ WqtH, unsigned short* __restrict__ WqtL,
    unsigned short* __restrict__ WktH, unsigned short* __restrict__ WktL,
    unsigned short* __restrict__ Wvt,  unsigned short* __restrict__ WOt)
{
    __shared__ float Ts[64][65];
    const int t     = threadIdx.x;
    const int which = blockIdx.z >> 4;
    const int z     = blockIdx.z & 15;
    const int r0    = blockIdx.x * 64;

    const float* in;
    unsigned short *oh, *ol;
    int z_mult, rstride;
    if (which == 0)      { in = WQ; oh = WqtH; ol = WqtL; z_mult = 65536; rstride = 64; }
    else if (which == 1) { in = WK; oh = WktH; ol = WktL; z_mult = 65536; rstride = 64; }
    else if (which == 2) { in = WV; oh = Wvt;  ol = nullptr; z_mult = 65536; rstride = 64; }
    else                 { in = WO; oh = WOt;  ol = nullptr; z_mult = 64;    rstride = 1024; }

    const float* src = in + (size_t)z * z_mult;
#pragma unroll
    for (int i = 0; i < 4; ++i) {
        const int row = (t >> 4) + i * 16;
        const int col = (t & 15) * 4;
        const float4 v = *(const float4*)&src[(size_t)(r0 + row) * rstride + col];
        Ts[row][col + 0] = v.x; Ts[row][col + 1] = v.y;
        Ts[row][col + 2] = v.z; Ts[row][col + 3] = v.w;
    }
    __syncthreads();
#pragma unroll
    for (int i = 0; i < 4; ++i) {
        const int c  = (t >> 4) + i * 16;
        const int rb = (t & 15) * 4;
        ushort4v hv, lv;
#pragma unroll
        for (int j = 0; j < 4; ++j) {
            const float x = Ts[rb + j][c];
            const unsigned short h = f2bf(x);
            hv[j] = h;
            lv[j] = f2bf(x - bf2f(h));
        }
        const size_t o = (size_t)(z * 64 + c) * 1024 + r0 + rb;
        *(ushort4v*)&oh[o] = hv;
        if (ol) *(ushort4v*)&ol[o] = lv;
    }
}

// ---------------------------------------------------------------------------
// bf16 MFMA GEMM core (global_load_lds width=16 staging).
// EPI=0: fp32 -> C.   EPI=1: bf16 hi/lo split -> O1/O2 (bit-identical to
// fp32-store + conv_k, since fp32 store/reload is exact and f2bf is the same).
// ---------------------------------------------------------------------------
template <bool SPLIT, int EPI>
__device__ __forceinline__ void gemm_core(unsigned short* __restrict__ sm,
                                          const unsigned short* __restrict__ Ah,
                                          const unsigned short* __restrict__ Al,
                                          const unsigned short* __restrict__ Bh,
                                          const unsigned short* __restrict__ Bl,
                                          float* __restrict__ C,
                                          unsigned short* __restrict__ O1,
                                          unsigned short* __restrict__ O2,
                                          int m0, int n0)
{
    unsigned short* AsH = sm;            // [128][32]
    unsigned short* BsH = sm + 4096;
    unsigned short* AsL = sm + 8192;     // SPLIT only
    unsigned short* BsL = sm + 12288;

    const int t    = threadIdx.x;
    const int wave = t >> 6;
    const int lane = t & 63;
    const int quad = lane >> 4;
    const int l15  = lane & 15;
    const int wm   = (wave & 1) * 64;
    const int wn   = (wave >> 1) * 64;

    float4v acc[4][4];
#pragma unroll
    for (int mi = 0; mi < 4; ++mi)
#pragma unroll
        for (int ni = 0; ni < 4; ++ni)
#pragma unroll
            for (int r = 0; r < 4; ++r) acc[mi][ni][r] = 0.f;

    for (int k0 = 0; k0 < 1024; k0 += 32) {
        __syncthreads();   // prior iteration's LDS reads complete
#pragma unroll
        for (int i = 0; i < 2; ++i) {
            const int c   = t + 256 * i;
            const int row = c >> 2;
            const int kc  = (c & 3) * 8;
            const int lb  = (i * 256 + wave * 64) * 8;   // wave-uniform base (shorts)
            gl_lds16(&Ah[(size_t)(m0 + row) * 1024 + k0 + kc], AsH + lb);
            gl_lds16(&Bh[(size_t)(n0 + row) * 1024 + k0 + kc], BsH + lb);
            if (SPLIT) {
                gl_lds16(&Al[(size_t)(m0 + row) * 1024 + k0 + kc], AsL + lb);
                gl_lds16(&Bl[(size_t)(n0 + row) * 1024 + k0 + kc], BsL + lb);
            }
        }
        __syncthreads();   // vmcnt drained before barrier -> data visible

        short8 afh[4], bfh[4], afl[4], bfl[4];
#pragma unroll
        for (int mi = 0; mi < 4; ++mi)
            afh[mi] = *(const short8*)&AsH[(wm + mi * 16 + l15) * 32 + quad * 8];
#pragma unroll
        for (int ni = 0; ni < 4; ++ni)
            bfh[ni] = *(const short8*)&BsH[(wn + ni * 16 + l15) * 32 + quad * 8];
        if (SPLIT) {
#pragma unroll
            for (int mi = 0; mi < 4; ++mi)
                afl[mi] = *(const short8*)&AsL[(wm + mi * 16 + l15) * 32 + quad * 8];
#pragma unroll
            for (int ni = 0; ni < 4; ++ni)
                bfl[ni] = *(const short8*)&BsL[(wn + ni * 16 + l15) * 32 + quad * 8];
        }

#pragma unroll
        for (int mi = 0; mi < 4; ++mi)
#pragma unroll
            for (int ni = 0; ni < 4; ++ni) {
                acc[mi][ni] = __builtin_amdgcn_mfma_f32_16x16x32_bf16(
                    afh[mi], bfh[ni], acc[mi][ni], 0, 0, 0);
                if (SPLIT) {
                    acc[mi][ni] = __builtin_amdgcn_mfma_f32_16x16x32_bf16(
                        afh[mi], bfl[ni], acc[mi][ni], 0, 0, 0);
                    acc[mi][ni] = __builtin_amdgcn_mfma_f32_16x16x32_bf16(
                        afl[mi], bfh[ni], acc[mi][ni], 0, 0, 0);
                }
            }
    }

#pragma unroll
    for (int mi = 0; mi < 4; ++mi)
#pragma unroll
        for (int r = 0; r < 4; ++r) {
            const int m = m0 + wm + mi * 16 + quad * 4 + r;
            if (EPI == 0) {
                float* cp = C + (size_t)m * 1024 + n0 + wn + l15;
#pragma unroll
                for (int ni = 0; ni < 4; ++ni) cp[ni * 16] = acc[mi][ni][r];
            } else {
                unsigned short* o1 = O1 + (size_t)m * 1024 + n0 + wn + l15;
                unsigned short* o2 = O2 + (size_t)m * 1024 + n0 + wn + l15;
#pragma unroll
                for (int ni = 0; ni < 4; ++ni) {
                    const float v = acc[mi][ni][r];
                    const unsigned short hh = f2bf(v);
                    o1[ni * 16] = hh;
                    o2[ni * 16] = f2bf(v - bf2f(hh));
                }
            }
        }
}

// Fused projections: z=0 Q(split->fp32 Qc), z=1 K(split->bf16 hi/lo direct),
// z=2 V(plain->fp32 Vc)
__global__ __launch_bounds__(256) void proj_mfma(
    const unsigned short* __restrict__ XqH, const unsigned short* __restrict__ XqL,
    const unsigned short* __restrict__ XkH, const unsigned short* __restrict__ XkL,
    const unsigned short* __restrict__ Xv,
    const unsigned short* __restrict__ WqtH, const unsigned short* __restrict__ WqtL,
    const unsigned short* __restrict__ WktH, const unsigned short* __restrict__ WktL,
    const unsigned short* __restrict__ Wvt,
    float* __restrict__ Qc,
    unsigned short* __restrict__ KHg, unsigned short* __restrict__ KLg,
    float* __restrict__ Vc)
{
    __shared__ __align__(16) unsigned short smem[4 * 4096];
    const int m0 = blockIdx.x * 128, n0 = blockIdx.y * 128;
    if (blockIdx.z == 0)
        gemm_core<true, 0>(smem, XqH, XqL, WqtH, WqtL, Qc, nullptr, nullptr, m0, n0);
    else if (blockIdx.z == 1)
        gemm_core<true, 1>(smem, XkH, XkL, WktH, WktL, nullptr, KHg, KLg, m0, n0);
    else
        gemm_core<false, 0>(smem, Xv, nullptr, Wvt, nullptr, Vc, nullptr, nullptr, m0, n0);
}

__global__ __launch_bounds__(256) void out_gemm_mfma(
    const unsigned short* __restrict__ Ocb,
    const unsigned short* __restrict__ WOt,
    float* __restrict__ out)
{
    __shared__ __align__(16) unsigned short smem[2 * 4096];
    gemm_core<false, 0>(smem, Ocb, nullptr, WOt, nullptr, out, nullptr, nullptr,
                        blockIdx.x * 128, blockIdx.y * 128);
}

// ---------------------------------------------------------------------------
// MFMA flash attention — ROUND-8 VERBATIM (best measured: 140.5 µs, VGPR 76,
// occupancy 29.8%).  Pure-vector staging from pre-split K / pre-transposed V,
// register prefetch, MFMA-folded row-sum, base-2 softmax (per-tile SCL mul),
// diagonal-only mask branch, unconditional alpha rescale, f2bf P-pack.
// NOTE (r10/r11): moving SCL into the Q fragments ("pre-scale") raised VGPR
// 76->92/100 and dropped occupancy to ~20% -> 160 µs.  Keep SCL per-tile.
// ---------------------------------------------------------------------------
__global__ __launch_bounds__(256) void attn_mfma(const float* __restrict__ Qc,
                                                 const unsigned short* __restrict__ KHg,
                                                 const unsigned short* __restrict__ KLg,
                                                 const unsigned short* __restrict__ Vtg,
                                                 unsigned short* __restrict__ Ocb)
{
    __shared__ __align__(16) short Khi[64][72];
    __shared__ __align__(16) short Klo[64][72];
    __shared__ __align__(16) short Vts[64][72];   // [dk][key]
    __shared__ __align__(16) short Pb[4][16][72];

    const int bid = blockIdx.x;
    const int h   = bid & 15;
    const int qt  = 63 - (bid >> 4);   // longest tiles dispatch first
    const int q0  = qt * 64;

    const int t    = threadIdx.x;
    const int wave = t >> 6;
    const int lane = t & 63;
    const int quad = lane >> 4;
    const int l15  = lane & 15;

    constexpr float SCL = 0.18033688011112042f;   // 0.125 * log2(e)

    // Q A-fragments, split hi/lo from fp32 (once per block)
    short8 qhi[2], qlo[2];
    {
        const int qrow = q0 + wave * 16 + l15;
        const float* qp = Qc + (size_t)qrow * DMODEL + h * 64 + quad * 8;
#pragma unroll
        for (int ks = 0; ks < 2; ++ks) {
            float4 a = *(const float4*)(qp + ks * 32);
            float4 b = *(const float4*)(qp + ks * 32 + 4);
            const float xs[8] = {a.x, a.y, a.z, a.w, b.x, b.y, b.z, b.w};
#pragma unroll
            for (int j = 0; j < 8; ++j) {
                const unsigned short hi = f2bf(xs[j]);
                const unsigned short lo = f2bf(xs[j] - bf2f(hi));
                qhi[ks][j] = (short)hi;
                qlo[ks][j] = (short)lo;
            }
        }
    }

    // all-ones B fragment: B[k][0] = 1.0, other cols 0  (row-sum MFMA)
    short8 bones;
    {
        const short ob = (l15 == 0) ? (short)0x3F80 : (short)0;
#pragma unroll
        for (int j = 0; j < 8; ++j) bones[j] = ob;
    }

    float m_r[4] = {-1e30f, -1e30f, -1e30f, -1e30f};
    float4v lacc;
    float4v oacc[4];
#pragma unroll
    for (int r = 0; r < 4; ++r) lacc[r] = 0.f;
#pragma unroll
    for (int nt = 0; nt < 4; ++nt)
#pragma unroll
        for (int r = 0; r < 4; ++r) oacc[nt][r] = 0.f;

    // staging assignment: thread covers rows {srow, srow+32}, 16B col chunk
    const int srow = t >> 3;
    const int soff = (t & 7) * 8;

    // prefetch registers, initial load for jt = 0
    ushort8 kh[2], kl[2], vt[2];
#pragma unroll
    for (int i = 0; i < 2; ++i) {
        const int row = srow + 32 * i;
        kh[i] = *(const ushort8*)&KHg[(size_t)row * 1024 + h * 64 + soff];
        kl[i] = *(const ushort8*)&KLg[(size_t)row * 1024 + h * 64 + soff];
        vt[i] = *(const ushort8*)&Vtg[(size_t)(h * 64 + row) * 4096 + soff];
    }

    for (int jt = 0; jt <= qt; ++jt) {
        const int j0 = jt * 64;
        // --- stage prefetched vectors (conflict-free ds_write_b128) ---
#pragma unroll
        for (int i = 0; i < 2; ++i) {
            const int row = srow + 32 * i;
            *(ushort8*)&Khi[row][soff] = kh[i];
            *(ushort8*)&Klo[row][soff] = kl[i];
            *(ushort8*)&Vts[row][soff] = vt[i];
        }
        __syncthreads();

        // --- prefetch next tile (overlaps compute below) ---
        if (jt < qt) {
            const int jn = j0 + 64;
#pragma unroll
            for (int i = 0; i < 2; ++i) {
                const int row = srow + 32 * i;
                kh[i] = *(const ushort8*)&KHg[(size_t)(jn + row) * 1024 + h * 64 + soff];
                kl[i] = *(const ushort8*)&KLg[(size_t)(jn + row) * 1024 + h * 64 + soff];
                vt[i] = *(const ushort8*)&Vtg[(size_t)(h * 64 + row) * 4096 + jn + soff];
            }
        }

        // --- S = Q K^T (split bf16, fp32 accum) ---
        float4v sacc[4];
#pragma unroll
        for (int nt = 0; nt < 4; ++nt)
#pragma unroll
            for (int r = 0; r < 4; ++r) sacc[nt][r] = 0.f;
#pragma unroll
        for (int nt = 0; nt < 4; ++nt) {
            const int key = nt * 16 + l15;
#pragma unroll
            for (int ks = 0; ks < 2; ++ks) {
                const short8 bh = *(const short8*)&Khi[key][ks * 32 + quad * 8];
                const short8 bl = *(const short8*)&Klo[key][ks * 32 + quad * 8];
                sacc[nt] = __builtin_amdgcn_mfma_f32_16x16x32_bf16(qhi[ks], bh, sacc[nt], 0, 0, 0);
                sacc[nt] = __builtin_amdgcn_mfma_f32_16x16x32_bf16(qhi[ks], bl, sacc[nt], 0, 0, 0);
                sacc[nt] = __builtin_amdgcn_mfma_f32_16x16x32_bf16(qlo[ks], bh, sacc[nt], 0, 0, 0);
            }
        }

        // --- scale to base-2; causal mask only on diagonal tile ---
        if (jt == qt) {
#pragma unroll
            for (int nt = 0; nt < 4; ++nt) {
                const int jg = j0 + nt * 16 + l15;
#pragma unroll
                for (int r = 0; r < 4; ++r) {
                    const int qg = q0 + wave * 16 + quad * 4 + r;
                    const float v = sacc[nt][r] * SCL;
                    sacc[nt][r] = (jg > qg) ? -1e9f : v;
                }
            }
        } else {
#pragma unroll
            for (int nt = 0; nt < 4; ++nt)
#pragma unroll
                for (int r = 0; r < 4; ++r)
                    sacc[nt][r] *= SCL;
        }

        // --- online softmax max-path ---
        float rmax[4];
#pragma unroll
        for (int r = 0; r < 4; ++r)
            rmax[r] = fmaxf(fmaxf(sacc[0][r], sacc[1][r]), fmaxf(sacc[2][r], sacc[3][r]));
#pragma unroll
        for (int off = 1; off < 16; off <<= 1)
#pragma unroll
            for (int r = 0; r < 4; ++r)
                rmax[r] = fmaxf(rmax[r], __shfl_xor(rmax[r], off));

        float alpha[4];
#pragma unroll
        for (int r = 0; r < 4; ++r) {
            const float mn = fmaxf(m_r[r], rmax[r]);
            alpha[r] = fexp2(m_r[r] - mn);
            m_r[r] = mn;
        }

        // --- exp2 (sum folded into PV MFMA) ---
#pragma unroll
        for (int nt = 0; nt < 4; ++nt)
#pragma unroll
            for (int r = 0; r < 4; ++r)
                sacc[nt][r] = fexp2(sacc[nt][r] - m_r[r]);

#pragma unroll
        for (int r = 0; r < 4; ++r) lacc[r] *= alpha[r];
#pragma unroll
        for (int nt = 0; nt < 4; ++nt)
#pragma unroll
            for (int r = 0; r < 4; ++r)
                oacc[nt][r] *= alpha[r];

        // --- P (C-layout) -> per-wave LDS strip -> A-layout (f2bf, RNE) ---
#pragma unroll
        for (int nt = 0; nt < 4; ++nt)
#pragma unroll
            for (int r = 0; r < 4; ++r)
                Pb[wave][quad * 4 + r][nt * 16 + l15] = (short)f2bf(sacc[nt][r]);
        __asm__ volatile("s_waitcnt lgkmcnt(0)" ::: "memory");

        // --- O += P @ V, and l += P @ 1 ---
        short8 af[2];
        af[0] = *(const short8*)&Pb[wave][l15][quad * 8];
        af[1] = *(const short8*)&Pb[wave][l15][32 + quad * 8];
#pragma unroll
        for (int nt = 0; nt < 4; ++nt) {
            const int dk = nt * 16 + l15;
#pragma unroll
            for (int ks = 0; ks < 2; ++ks) {
                const short8 bv = *(const short8*)&Vts[dk][ks * 32 + quad * 8];
                oacc[nt] = __builtin_amdgcn_mfma_f32_16x16x32_bf16(af[ks], bv, oacc[nt], 0, 0, 0);
            }
        }
        lacc = __builtin_amdgcn_mfma_f32_16x16x32_bf16(af[0], bones, lacc, 0, 0, 0);
        lacc = __builtin_amdgcn_mfma_f32_16x16x32_bf16(af[1], bones, lacc, 0, 0, 0);
        __syncthreads();   // LDS tiles free before restaging
    }

    // --- epilogue: broadcast l from col-0 lanes, normalize, write bf16 ---
#pragma unroll
    for (int r = 0; r < 4; ++r) {
        const float lsum = __shfl(lacc[r], (lane & 48));   // lane quad*16 (l15==0)
        const float inv  = 1.0f / lsum;
        const int qg = q0 + wave * 16 + quad * 4 + r;
        unsigned short* op = Ocb + (size_t)qg * DMODEL + h * 64 + l15;
#pragma unroll
        for (int nt = 0; nt < 4; ++nt)
            op[nt * 16] = f2bf(oacc[nt][r] * inv);
    }
}

extern "C" void kernel_launch(void* const* d_in, const int* in_sizes, int n_in,
                              void* d_out, int out_size, void* d_ws, size_t ws_size,
                              hipStream_t stream)
{
    const float* Q  = (const float*)d_in[0];
    const float* K  = (const float*)d_in[1];
    const float* V  = (const float*)d_in[2];
    const float* WQ = (const float*)d_in[3];
    const float* WK = (const float*)d_in[4];
    const float* WV = (const float*)d_in[5];
    const float* WO = (const float*)d_in[6];

    float* out = (float*)d_out;

    // Workspace carve-up (108 MB).  KHg/KLg take the old fp32-Kc slot
    // (fresh memory — NOT aliased with any buffer live during proj_mfma,
    // since the K epilogue now writes them during proj itself).
    const size_t SD4 = (size_t)S * DMODEL * 4;       // fp32 S x D  (16 MB)
    const size_t SD2 = (size_t)S * DMODEL * 2;       // bf16 S x D  ( 8 MB)
    const size_t W2  = (size_t)DMODEL * DMODEL * 2;  // bf16 D x D  ( 2 MB)
    char* p = (char*)d_ws;
    auto take = [&](size_t b) { char* r = p; p += b; return r; };

    float* Qc = (float*)take(SD4);
    unsigned short* KHg = (unsigned short*)take(SD2);   // old Kc slot, 1st half
    unsigned short* KLg = (unsigned short*)take(SD2);   // old Kc slot, 2nd half
    float* Vc = (float*)take(SD4);
    unsigned short* XqH = (unsigned short*)take(SD2);
    unsigned short* XqL = (unsigned short*)take(SD2);
    unsigned short* XkH = (unsigned short*)take(SD2);
    unsigned short* XkL = (unsigned short*)take(SD2);
    unsigned short* Xv  = (unsigned short*)take(SD2);
    unsigned short* WqtH = (unsigned short*)take(W2);
    unsigned short* WqtL = (unsigned short*)take(W2);
    unsigned short* WktH = (unsigned short*)take(W2);
    unsigned short* WktL = (unsigned short*)take(W2);
    unsigned short* Wvt  = (unsigned short*)take(W2);
    unsigned short* WOt  = (unsigned short*)take(W2);
    unsigned short* Ocb  = (unsigned short*)take(SD2);
    // Vtg aliases Xv: dead after proj_mfma, transpose_v runs after (serialized).
    unsigned short* Vtg = Xv;

    // 1) input splits (Q,K hi/lo; V bf16)
    split_inputs<<<dim3(2048, 1, 3), 256, 0, stream>>>(Q, K, V,
                                                       XqH, XqL, XkH, XkL, Xv);
    // 2) all weight transposes in one launch
    transpose_w_all<<<dim3(16, 1, 64), 256, 0, stream>>>(
        WQ, WK, WV, WO, WqtH, WqtL, WktH, WktL, Wvt, WOt);
    // 3) projections: Q -> fp32 Qc; K -> bf16 hi/lo DIRECT; V -> fp32 Vc
    proj_mfma<<<dim3(S / 128, DMODEL / 128, 3), 256, 0, stream>>>(
        XqH, XqL, XkH, XkL, Xv, WqtH, WqtL, WktH, WktL, Wvt, Qc, KHg, KLg, Vc);
    // 4) pre-transpose V (validated);  conv_k eliminated by K epilogue
    transpose_v<<<dim3(S / 64, DMODEL / 64), 256, 0, stream>>>(Vc, Vtg);
    // 5) causal flash attention -> bf16 Ocb  (round-8 verbatim kernel)
    attn_mfma<<<dim3((S / 64) * H), 256, 0, stream>>>(Qc, KHg, KLg, Vtg, Ocb);
    // 6) output projection
    out_gemm_mfma<<<dim3(S / 128, DMODEL / 128), 256, 0, stream>>>(Ocb, WOt, out);
}